// Round 1
// 149.733 us; speedup vs baseline: 1.0250x; 1.0250x over previous
//
#include <hip/hip_runtime.h>

// Problem constants: n_class=32, n_support=16, n_query=16, D=1024;
// query rows Q = 512. Output (512, 32, 1024) fp32.
constexpr int NC = 32, NS = 16, NQ = 512, D = 1024;
constexpr int QPB = 8;     // queries per block = 4 waves x 2 queries/wave
constexpr int F4H = 128;   // float4 per support row per d-half (512 floats)

__device__ __forceinline__ float rcp1p(float t) {
    // 1 / (exp2(t) + 1)
    return __builtin_amdgcn_rcpf(__builtin_amdgcn_exp2f(t) + 1.f);
}

__global__ __launch_bounds__(256, 4)
void proto_attn_kernel(const float* __restrict__ data, float* __restrict__ out) {
    const int c    = blockIdx.x;   // class
    const int qt   = blockIdx.y;   // query tile
    const int tid  = threadIdx.x;
    const int wave = tid >> 6;
    const int lane = tid & 63;

    // One d-half of support[c]: 16 rows x 512 floats = 32 KB.
    // 32 KB/block -> 4 blocks/CU (VGPR-limited), vs 2 blocks/CU at 64 KB.
    __shared__ float4 sup4[NS * F4H];

    const float4* sg = reinterpret_cast<const float4*>(data + (size_t)c * NS * D);

    // ---- load this wave's two query rows, pre-scaled by K = 2*log2(e) ----
    // tanh(x) = 1 - 2/(exp2(K*x)+1)
    const float K = 2.88539008177792681472f;
    const int q0 = qt * QPB + wave * 2;
    const float4* qg0 = reinterpret_cast<const float4*>(data + (size_t)(NC * NS + q0) * D);
    const float4* qg1 = qg0 + 256;   // next query row (1024 floats)
    float4 qa[4], qb[4];
    #pragma unroll
    for (int j = 0; j < 4; ++j) {
        float4 t0 = qg0[lane + 64 * j];
        float4 t1 = qg1[lane + 64 * j];
        qa[j] = make_float4(t0.x * K, t0.y * K, t0.z * K, t0.w * K);
        qb[j] = make_float4(t1.x * K, t1.y * K, t1.z * K, t1.w * K);
    }

    // ---- stage d-half 0 ----
    #pragma unroll
    for (int i = 0; i < 8; ++i) {
        int idx = tid + 256 * i;
        sup4[idx] = sg[((idx >> 7) << 8) + (idx & 127)];
    }
    __syncthreads();

    // ---- partial scores over d-half 0 (independent per-component chains) ----
    float sc0[NS], sc1[NS];
    #pragma unroll
    for (int s = 0; s < NS; ++s) {
        float4 t0 = make_float4(0.f, 0.f, 0.f, 0.f);
        float4 t1 = make_float4(0.f, 0.f, 0.f, 0.f);
        #pragma unroll
        for (int jj = 0; jj < 2; ++jj) {
            float4 sv = sup4[s * F4H + lane + 64 * jj];
            float4 qA = qa[jj], qB = qb[jj];
            t0.x += rcp1p(sv.x * qA.x); t0.y += rcp1p(sv.y * qA.y);
            t0.z += rcp1p(sv.z * qA.z); t0.w += rcp1p(sv.w * qA.w);
            t1.x += rcp1p(sv.x * qB.x); t1.y += rcp1p(sv.y * qB.y);
            t1.z += rcp1p(sv.z * qB.z); t1.w += rcp1p(sv.w * qB.w);
        }
        sc0[s] = (t0.x + t0.y) + (t0.z + t0.w);
        sc1[s] = (t1.x + t1.y) + (t1.z + t1.w);
    }
    __syncthreads();   // all waves done reading half 0

    // ---- stage d-half 1, finish scores ----
    #pragma unroll
    for (int i = 0; i < 8; ++i) {
        int idx = tid + 256 * i;
        sup4[idx] = sg[((idx >> 7) << 8) + 128 + (idx & 127)];
    }
    __syncthreads();

    #pragma unroll
    for (int s = 0; s < NS; ++s) {
        float4 t0 = make_float4(0.f, 0.f, 0.f, 0.f);
        float4 t1 = make_float4(0.f, 0.f, 0.f, 0.f);
        #pragma unroll
        for (int jj = 0; jj < 2; ++jj) {
            float4 sv = sup4[s * F4H + lane + 64 * jj];
            float4 qA = qa[2 + jj], qB = qb[2 + jj];
            t0.x += rcp1p(sv.x * qA.x); t0.y += rcp1p(sv.y * qA.y);
            t0.z += rcp1p(sv.z * qA.z); t0.w += rcp1p(sv.w * qA.w);
            t1.x += rcp1p(sv.x * qB.x); t1.y += rcp1p(sv.y * qB.y);
            t1.z += rcp1p(sv.z * qB.z); t1.w += rcp1p(sv.w * qB.w);
        }
        sc0[s] += (t0.x + t0.y) + (t0.z + t0.w);
        sc1[s] += (t1.x + t1.y) + (t1.z + t1.w);
    }

    // ---- wave64 butterfly reduction: sc[q][s] = D - 2 * sum_d 1/(exp2+1) ----
    #pragma unroll
    for (int s = 0; s < NS; ++s) {
        float r0 = sc0[s], r1 = sc1[s];
        #pragma unroll
        for (int m = 32; m >= 1; m >>= 1) {
            r0 += __shfl_xor(r0, m, 64);
            r1 += __shfl_xor(r1, m, 64);
        }
        sc0[s] = (float)D - 2.f * r0;
        sc1[s] = (float)D - 2.f * r1;
    }

    // ---- softmax over s (16 values, replicated in every lane) ----
    const float L2E = 1.44269504088896340736f;
    float m0 = sc0[0], m1 = sc1[0];
    #pragma unroll
    for (int s = 1; s < NS; ++s) { m0 = fmaxf(m0, sc0[s]); m1 = fmaxf(m1, sc1[s]); }
    float sum0 = 0.f, sum1 = 0.f;
    #pragma unroll
    for (int s = 0; s < NS; ++s) {
        sc0[s] = __builtin_amdgcn_exp2f((sc0[s] - m0) * L2E);
        sc1[s] = __builtin_amdgcn_exp2f((sc1[s] - m1) * L2E);
        sum0 += sc0[s];
        sum1 += sc1[s];
    }
    const float inv0 = __builtin_amdgcn_rcpf(sum0);
    const float inv1 = __builtin_amdgcn_rcpf(sum1);
    #pragma unroll
    for (int s = 0; s < NS; ++s) { sc0[s] *= inv0; sc1[s] *= inv1; }

    float* orow0 = out + ((size_t)q0 * NC + c) * D;
    float* orow1 = orow0 + (size_t)NC * D;

    // ---- proto over d-half 1 (currently staged), store ----
    {
        float4 o0[2], o1[2];
        o0[0] = o0[1] = o1[0] = o1[1] = make_float4(0.f, 0.f, 0.f, 0.f);
        #pragma unroll
        for (int s = 0; s < NS; ++s) {
            const float a0 = sc0[s], a1 = sc1[s];
            #pragma unroll
            for (int jj = 0; jj < 2; ++jj) {
                float4 sv = sup4[s * F4H + lane + 64 * jj];
                o0[jj].x += a0 * sv.x; o0[jj].y += a0 * sv.y;
                o0[jj].z += a0 * sv.z; o0[jj].w += a0 * sv.w;
                o1[jj].x += a1 * sv.x; o1[jj].y += a1 * sv.y;
                o1[jj].z += a1 * sv.z; o1[jj].w += a1 * sv.w;
            }
        }
        float4* og0 = reinterpret_cast<float4*>(orow0) + 128;
        float4* og1 = reinterpret_cast<float4*>(orow1) + 128;
        #pragma unroll
        for (int jj = 0; jj < 2; ++jj) {
            og0[lane + 64 * jj] = o0[jj];
            og1[lane + 64 * jj] = o1[jj];
        }
    }
    __syncthreads();   // all waves done reading half 1

    // ---- restage d-half 0, proto, store ----
    #pragma unroll
    for (int i = 0; i < 8; ++i) {
        int idx = tid + 256 * i;
        sup4[idx] = sg[((idx >> 7) << 8) + (idx & 127)];
    }
    __syncthreads();
    {
        float4 o0[2], o1[2];
        o0[0] = o0[1] = o1[0] = o1[1] = make_float4(0.f, 0.f, 0.f, 0.f);
        #pragma unroll
        for (int s = 0; s < NS; ++s) {
            const float a0 = sc0[s], a1 = sc1[s];
            #pragma unroll
            for (int jj = 0; jj < 2; ++jj) {
                float4 sv = sup4[s * F4H + lane + 64 * jj];
                o0[jj].x += a0 * sv.x; o0[jj].y += a0 * sv.y;
                o0[jj].z += a0 * sv.z; o0[jj].w += a0 * sv.w;
                o1[jj].x += a1 * sv.x; o1[jj].y += a1 * sv.y;
                o1[jj].z += a1 * sv.z; o1[jj].w += a1 * sv.w;
            }
        }
        float4* og0 = reinterpret_cast<float4*>(orow0);
        float4* og1 = reinterpret_cast<float4*>(orow1);
        #pragma unroll
        for (int jj = 0; jj < 2; ++jj) {
            og0[lane + 64 * jj] = o0[jj];
            og1[lane + 64 * jj] = o1[jj];
        }
    }
}

extern "C" void kernel_launch(void* const* d_in, const int* in_sizes, int n_in,
                              void* d_out, int out_size, void* d_ws, size_t ws_size,
                              hipStream_t stream) {
    (void)in_sizes; (void)n_in; (void)out_size; (void)d_ws; (void)ws_size;
    const float* data = (const float*)d_in[0];
    float* out = (float*)d_out;
    dim3 grid(NC, NQ / QPB);   // 32 classes x 64 query tiles = 2048 blocks
    proto_attn_kernel<<<grid, dim3(256), 0, stream>>>(data, out);
}

// Round 2
// 143.292 us; speedup vs baseline: 1.0711x; 1.0449x over previous
//
#include <hip/hip_runtime.h>

// Problem constants: n_class=32, n_support=16, n_query=16, D=1024;
// query rows Q = 512. Output (512, 32, 1024) fp32.
constexpr int NC = 32, NS = 16, NQ = 512, D = 1024;
constexpr int QPB = 8;     // queries per block = 4 waves x 2 queries/wave
constexpr int F4H = 128;   // float4 per support row per d-half (512 floats)

// 1/(exp2(t0)+1) + 1/(exp2(t1)+1) with ONE rcp:
// x=exp2(t0)+1, y=exp2(t1)+1  ->  (x+y) / (x*y).
// Clamp t at 60 so x*y <= 2^121 < inf (tanh fully saturated far below t=60).
__device__ __forceinline__ float pair_term(float t0, float t1) {
    t0 = fminf(t0, 60.f);
    t1 = fminf(t1, 60.f);
    float x = __builtin_amdgcn_exp2f(t0) + 1.f;
    float y = __builtin_amdgcn_exp2f(t1) + 1.f;
    return (x + y) * __builtin_amdgcn_rcpf(x * y);
}

// launch_bounds(256, 2): empirically the 2nd arg caps VGPR at 256/k;
// k=2 -> 128 VGPR cap -> no spills (live state ~100), 4 waves/SIMD bucket.
// k=4 (VGPR cap 64) spilled ~37 floats/lane -> +108 MB scratch HBM traffic.
__global__ __launch_bounds__(256, 2)
void proto_attn_kernel(const float* __restrict__ data, float* __restrict__ out) {
    const int c    = blockIdx.x;   // class
    const int qt   = blockIdx.y;   // query tile
    const int tid  = threadIdx.x;
    const int wave = tid >> 6;
    const int lane = tid & 63;

    // One d-half of support[c]: 16 rows x 512 floats = 32 KB -> 4 blocks/CU.
    __shared__ float4 sup4[NS * F4H];

    const float4* sg = reinterpret_cast<const float4*>(data + (size_t)c * NS * D);

    // ---- load this wave's two query rows, pre-scaled by K = 2*log2(e) ----
    // tanh(x) = 1 - 2/(exp2(K*x)+1)
    const float K = 2.88539008177792681472f;
    const int q0 = qt * QPB + wave * 2;
    const float4* qg0 = reinterpret_cast<const float4*>(data + (size_t)(NC * NS + q0) * D);
    const float4* qg1 = qg0 + 256;   // next query row (1024 floats)
    float4 qa[4], qb[4];
    #pragma unroll
    for (int j = 0; j < 4; ++j) {
        float4 t0 = qg0[lane + 64 * j];
        float4 t1 = qg1[lane + 64 * j];
        qa[j] = make_float4(t0.x * K, t0.y * K, t0.z * K, t0.w * K);
        qb[j] = make_float4(t1.x * K, t1.y * K, t1.z * K, t1.w * K);
    }

    // ---- stage d-half 0 ----
    #pragma unroll
    for (int i = 0; i < 8; ++i) {
        int idx = tid + 256 * i;
        sup4[idx] = sg[((idx >> 7) << 8) + (idx & 127)];
    }
    __syncthreads();

    // ---- partial scores over d-half 0 ----
    float sc0[NS], sc1[NS];
    #pragma unroll
    for (int s = 0; s < NS; ++s) {
        float u0 = 0.f, v0 = 0.f, u1 = 0.f, v1 = 0.f;   // independent chains
        #pragma unroll
        for (int jj = 0; jj < 2; ++jj) {
            float4 sv = sup4[s * F4H + lane + 64 * jj];
            float4 qA = qa[jj], qB = qb[jj];
            u0 += pair_term(sv.x * qA.x, sv.y * qA.y);
            v0 += pair_term(sv.z * qA.z, sv.w * qA.w);
            u1 += pair_term(sv.x * qB.x, sv.y * qB.y);
            v1 += pair_term(sv.z * qB.z, sv.w * qB.w);
        }
        sc0[s] = u0 + v0;
        sc1[s] = u1 + v1;
    }
    __syncthreads();   // all waves done reading half 0

    // ---- stage d-half 1, finish scores ----
    #pragma unroll
    for (int i = 0; i < 8; ++i) {
        int idx = tid + 256 * i;
        sup4[idx] = sg[((idx >> 7) << 8) + 128 + (idx & 127)];
    }
    __syncthreads();

    #pragma unroll
    for (int s = 0; s < NS; ++s) {
        float u0 = 0.f, v0 = 0.f, u1 = 0.f, v1 = 0.f;
        #pragma unroll
        for (int jj = 0; jj < 2; ++jj) {
            float4 sv = sup4[s * F4H + lane + 64 * jj];
            float4 qA = qa[2 + jj], qB = qb[2 + jj];
            u0 += pair_term(sv.x * qA.x, sv.y * qA.y);
            v0 += pair_term(sv.z * qA.z, sv.w * qA.w);
            u1 += pair_term(sv.x * qB.x, sv.y * qB.y);
            v1 += pair_term(sv.z * qB.z, sv.w * qB.w);
        }
        sc0[s] += u0 + v0;
        sc1[s] += u1 + v1;
    }

    // ---- wave64 butterfly reduction: sc[q][s] = D - 2 * sum_d 1/(exp2+1) ----
    #pragma unroll
    for (int s = 0; s < NS; ++s) {
        float r0 = sc0[s], r1 = sc1[s];
        #pragma unroll
        for (int m = 32; m >= 1; m >>= 1) {
            r0 += __shfl_xor(r0, m, 64);
            r1 += __shfl_xor(r1, m, 64);
        }
        sc0[s] = (float)D - 2.f * r0;
        sc1[s] = (float)D - 2.f * r1;
    }

    // ---- softmax over s (16 values, replicated in every lane) ----
    const float L2E = 1.44269504088896340736f;
    float m0 = sc0[0], m1 = sc1[0];
    #pragma unroll
    for (int s = 1; s < NS; ++s) { m0 = fmaxf(m0, sc0[s]); m1 = fmaxf(m1, sc1[s]); }
    float sum0 = 0.f, sum1 = 0.f;
    #pragma unroll
    for (int s = 0; s < NS; ++s) {
        sc0[s] = __builtin_amdgcn_exp2f((sc0[s] - m0) * L2E);
        sc1[s] = __builtin_amdgcn_exp2f((sc1[s] - m1) * L2E);
        sum0 += sc0[s];
        sum1 += sc1[s];
    }
    const float inv0 = __builtin_amdgcn_rcpf(sum0);
    const float inv1 = __builtin_amdgcn_rcpf(sum1);
    #pragma unroll
    for (int s = 0; s < NS; ++s) { sc0[s] *= inv0; sc1[s] *= inv1; }

    float* orow0 = out + ((size_t)q0 * NC + c) * D;
    float* orow1 = orow0 + (size_t)NC * D;

    // ---- proto over d-half 1 (currently staged), store ----
    {
        float4 o0[2], o1[2];
        o0[0] = o0[1] = o1[0] = o1[1] = make_float4(0.f, 0.f, 0.f, 0.f);
        #pragma unroll
        for (int s = 0; s < NS; ++s) {
            const float a0 = sc0[s], a1 = sc1[s];
            #pragma unroll
            for (int jj = 0; jj < 2; ++jj) {
                float4 sv = sup4[s * F4H + lane + 64 * jj];
                o0[jj].x += a0 * sv.x; o0[jj].y += a0 * sv.y;
                o0[jj].z += a0 * sv.z; o0[jj].w += a0 * sv.w;
                o1[jj].x += a1 * sv.x; o1[jj].y += a1 * sv.y;
                o1[jj].z += a1 * sv.z; o1[jj].w += a1 * sv.w;
            }
        }
        float4* og0 = reinterpret_cast<float4*>(orow0) + 128;
        float4* og1 = reinterpret_cast<float4*>(orow1) + 128;
        #pragma unroll
        for (int jj = 0; jj < 2; ++jj) {
            og0[lane + 64 * jj] = o0[jj];
            og1[lane + 64 * jj] = o1[jj];
        }
    }
    __syncthreads();   // all waves done reading half 1

    // ---- restage d-half 0, proto, store ----
    #pragma unroll
    for (int i = 0; i < 8; ++i) {
        int idx = tid + 256 * i;
        sup4[idx] = sg[((idx >> 7) << 8) + (idx & 127)];
    }
    __syncthreads();
    {
        float4 o0[2], o1[2];
        o0[0] = o0[1] = o1[0] = o1[1] = make_float4(0.f, 0.f, 0.f, 0.f);
        #pragma unroll
        for (int s = 0; s < NS; ++s) {
            const float a0 = sc0[s], a1 = sc1[s];
            #pragma unroll
            for (int jj = 0; jj < 2; ++jj) {
                float4 sv = sup4[s * F4H + lane + 64 * jj];
                o0[jj].x += a0 * sv.x; o0[jj].y += a0 * sv.y;
                o0[jj].z += a0 * sv.z; o0[jj].w += a0 * sv.w;
                o1[jj].x += a1 * sv.x; o1[jj].y += a1 * sv.y;
                o1[jj].z += a1 * sv.z; o1[jj].w += a1 * sv.w;
            }
        }
        float4* og0 = reinterpret_cast<float4*>(orow0);
        float4* og1 = reinterpret_cast<float4*>(orow1);
        #pragma unroll
        for (int jj = 0; jj < 2; ++jj) {
            og0[lane + 64 * jj] = o0[jj];
            og1[lane + 64 * jj] = o1[jj];
        }
    }
}

extern "C" void kernel_launch(void* const* d_in, const int* in_sizes, int n_in,
                              void* d_out, int out_size, void* d_ws, size_t ws_size,
                              hipStream_t stream) {
    (void)in_sizes; (void)n_in; (void)out_size; (void)d_ws; (void)ws_size;
    const float* data = (const float*)d_in[0];
    float* out = (float*)d_out;
    dim3 grid(NC, NQ / QPB);   // 32 classes x 64 query tiles = 2048 blocks
    proto_attn_kernel<<<grid, dim3(256), 0, stream>>>(data, out);
}